// Round 3
// baseline (504.966 us; speedup 1.0000x reference)
//
#include <hip/hip_runtime.h>
#include <hip/hip_bf16.h>

// ---------------------------------------------------------------------------
// MultiHeadAttn: B=4 S=2048 D=1024 H=16 DH=64, post-LN residual, no mask.
// fp16 MFMA pipeline: WT/X prep -> QKV GEMM -> flash attn -> Wo GEMM -> LN.
// ---------------------------------------------------------------------------

typedef __attribute__((ext_vector_type(8))) _Float16 half8;
typedef __attribute__((ext_vector_type(4))) _Float16 half4;
typedef __attribute__((ext_vector_type(4))) float f32x4;

#define D_MODEL 1024
#define SEQ     2048
#define NHEAD   16
#define HDIM    64
#define NTOK    8192          // B*S

// ---------------- async global->LDS, 16B, wave-uniform LDS base -------------
__device__ __forceinline__ void gload_lds16(const _Float16* g, _Float16* l) {
  __builtin_amdgcn_global_load_lds(
      (const __attribute__((address_space(1))) void*)g,
      (__attribute__((address_space(3))) void*)l, 16, 0, 0);
}

// Stage ROWS x 64-half tile (row-major, 128B/row) into LDS, XOR-swizzled
// source so that reads use granule (G ^ (row&7)). Dest is linear.
template<int ROWS>
__device__ __forceinline__ void stage_swz(const _Float16* __restrict__ g, int ldg,
                                          _Float16* lds, int t) {
  int lane = t & 63, w = t >> 6;
  int rr = lane >> 3, gcol = lane & 7;
#pragma unroll
  for (int i = 0; i < ROWS / 32; ++i) {
    int rowbase = i * 32 + w * 8;          // wave-uniform
    int row = rowbase + rr;                // per-lane
    int gsw = gcol ^ (row & 7);            // inverse swizzle on source
    gload_lds16(g + (size_t)row * ldg + gsw * 8, lds + rowbase * 64);
  }
}

// swizzled fragment read: 8 halves of row `row`, k-granule G = kk*4+(lane>>4)
__device__ __forceinline__ half8 lds_frag(const _Float16* base, int row, int kk, int lane) {
  int gg = (kk * 4 + (lane >> 4)) ^ (row & 7);
  return *(const half8*)(base + row * 64 + gg * 8);
}

// ---------------- weight transpose + fp32->fp16 (+fold SCALE into Wq) ------
__global__ __launch_bounds__(256)
void wtrans(const float* __restrict__ Wq, const float* __restrict__ Wk,
            const float* __restrict__ Wv, const float* __restrict__ Wo,
            _Float16* __restrict__ outAll) {
  __shared__ float tile[64][65];
  int z = blockIdx.z;
  const float* W = (z == 0) ? Wq : (z == 1) ? Wk : (z == 2) ? Wv : Wo;
  float scale = (z == 0) ? 0.125f : 1.0f;  // SCALE = 1/sqrt(64), exact pow2
  _Float16* out = outAll + (size_t)z * D_MODEL * D_MODEL;
  int n0 = blockIdx.x * 64, k0 = blockIdx.y * 64;
  int t = threadIdx.x, c = t & 63, rq = t >> 6;
#pragma unroll
  for (int i = 0; i < 16; ++i) {
    int r = rq * 16 + i;
    tile[r][c] = W[(size_t)(k0 + r) * D_MODEL + n0 + c];
  }
  __syncthreads();
#pragma unroll
  for (int i = 0; i < 16; ++i) {
    int r = rq * 16 + i;
    out[(size_t)(n0 + r) * D_MODEL + k0 + c] = (_Float16)(tile[c][r] * scale);
  }
}

// ---------------- h fp32 -> fp16 -------------------------------------------
__global__ __launch_bounds__(256)
void cvt_h(const float* __restrict__ in, _Float16* __restrict__ out) {
  int i = (blockIdx.x * 256 + threadIdx.x) * 4;
  float4 v = *(const float4*)&in[i];
  half4 o;
  o[0] = (_Float16)v.x; o[1] = (_Float16)v.y;
  o[2] = (_Float16)v.z; o[3] = (_Float16)v.w;
  *(half4*)&out[i] = o;
}

// ---------------- GEMM: C[M,N] = A[M,K] * Bt[N,K]^T, fp16 in, fp16 out -----
// 128x128 tile, BK=64, 4 waves (each 64x64), double-buffered LDS,
// global_load_lds x16B staging. grid=(N/128, M/128, batch).
__global__ __launch_bounds__(256, 2)
void gemm_tn(const _Float16* __restrict__ A, const _Float16* __restrict__ BtBase,
             _Float16* __restrict__ CBase, size_t strideB, size_t strideC) {
  constexpr int N = D_MODEL, K = D_MODEL;
  const _Float16* Bt = BtBase + strideB * blockIdx.z;
  _Float16* C = CBase + strideC * blockIdx.z;
  __shared__ __align__(16) _Float16 As[2][128 * 64];
  __shared__ __align__(16) _Float16 Bs[2][128 * 64];
  int t = threadIdx.x, lane = t & 63, w = t >> 6;
  int wr = w >> 1, wc = w & 1;
  const _Float16* Ab = A + (size_t)blockIdx.y * 128 * K;
  const _Float16* Bb = Bt + (size_t)blockIdx.x * 128 * K;

  f32x4 acc[4][4];
#pragma unroll
  for (int m = 0; m < 4; ++m)
#pragma unroll
    for (int n = 0; n < 4; ++n) acc[m][n] = f32x4{0.f, 0.f, 0.f, 0.f};

  stage_swz<128>(Ab, K, As[0], t);
  stage_swz<128>(Bb, K, Bs[0], t);
  __syncthreads();

  constexpr int NT = K / 64;
  for (int kt = 0; kt < NT; ++kt) {
    int cur = kt & 1;
    if (kt + 1 < NT) {
      stage_swz<128>(Ab + (kt + 1) * 64, K, As[cur ^ 1], t);
      stage_swz<128>(Bb + (kt + 1) * 64, K, Bs[cur ^ 1], t);
    }
#pragma unroll
    for (int kk = 0; kk < 2; ++kk) {
      half8 af[4], bf[4];
#pragma unroll
      for (int m = 0; m < 4; ++m)
        af[m] = lds_frag(As[cur], wr * 64 + m * 16 + (lane & 15), kk, lane);
#pragma unroll
      for (int n = 0; n < 4; ++n)
        bf[n] = lds_frag(Bs[cur], wc * 64 + n * 16 + (lane & 15), kk, lane);
#pragma unroll
      for (int m = 0; m < 4; ++m)
#pragma unroll
        for (int n = 0; n < 4; ++n)
          acc[m][n] = __builtin_amdgcn_mfma_f32_16x16x32_f16(af[m], bf[n], acc[m][n], 0, 0, 0);
    }
    __syncthreads();   // drains vmcnt (next bufs staged) + protects reuse
  }

  // epilogue: D row=(lane>>4)*4+r, col=lane&15 (m89-verified)
#pragma unroll
  for (int m = 0; m < 4; ++m)
#pragma unroll
    for (int n = 0; n < 4; ++n)
#pragma unroll
      for (int r = 0; r < 4; ++r) {
        int row = blockIdx.y * 128 + wr * 64 + m * 16 + (lane >> 4) * 4 + r;
        int col = blockIdx.x * 128 + wc * 64 + n * 16 + (lane & 15);
        C[(size_t)row * N + col] = (_Float16)acc[m][n][r];
      }
}

// ---------------- flash attention ------------------------------------------
// grid = (S/64, B*H), 256 threads = 4 waves, wave w owns q rows [w*16, w*16+16).
// KV-tile = 64. K staged swizzled via global_load_lds; V staged transposed.
__global__ __launch_bounds__(256, 2)
void attn(const _Float16* __restrict__ Q, const _Float16* __restrict__ Kg,
          const _Float16* __restrict__ V, _Float16* __restrict__ Ovec) {
  __shared__ __align__(16) _Float16 Ks[64 * 64];
  __shared__ __align__(16) _Float16 Vt[64][72];       // Vt[d][key], pad->2-way
  __shared__ __align__(16) _Float16 Plds[4][16][72];  // per-wave P tile
  int t = threadIdx.x, lane = t & 63, w = t >> 6;
  int q0 = blockIdx.x * 64;
  int bh = blockIdx.y, b = bh >> 4, h = bh & 15;
  size_t base = ((size_t)b * SEQ) * D_MODEL + h * HDIM;

  // Q fragments held in registers for the whole block
  half8 aQ[2];
  {
    int row = q0 + w * 16 + (lane & 15);
    const _Float16* qp = Q + base + (size_t)row * D_MODEL;
#pragma unroll
    for (int kk = 0; kk < 2; ++kk) aQ[kk] = *(const half8*)&qp[kk * 32 + 8 * (lane >> 4)];
  }

  float mr[4], lr[4];
  f32x4 accO[4];
#pragma unroll
  for (int r = 0; r < 4; ++r) { mr[r] = -1e30f; lr[r] = 0.f; }
#pragma unroll
  for (int n = 0; n < 4; ++n) accO[n] = f32x4{0.f, 0.f, 0.f, 0.f};

  for (int kv0 = 0; kv0 < SEQ; kv0 += 64) {
    __syncthreads();  // previous tile's Ks/Vt reads complete
    // stage K tile (swizzled, async)
    stage_swz<64>(Kg + base + (size_t)kv0 * D_MODEL, D_MODEL, Ks, t);
    // stage V transposed: Vt[d][key]
    {
      int key = t >> 3, d0 = (t & 7) * 8;
#pragma unroll
      for (int i = 0; i < 2; ++i) {
        int kr = key + i * 32;
        half8 vv = *(const half8*)&V[base + (size_t)(kv0 + kr) * D_MODEL + d0];
#pragma unroll
        for (int j = 0; j < 8; ++j) Vt[d0 + j][kr] = vv[j];
      }
    }
    __syncthreads();  // Ks (vmcnt drained) + Vt visible

    // scores S = Q K^T  (SCALE already folded into Wq)
    f32x4 s[4];
#pragma unroll
    for (int n = 0; n < 4; ++n) s[n] = f32x4{0.f, 0.f, 0.f, 0.f};
#pragma unroll
    for (int kk = 0; kk < 2; ++kk)
#pragma unroll
      for (int n = 0; n < 4; ++n) {
        half8 bK = lds_frag(Ks, n * 16 + (lane & 15), kk, lane);
        s[n] = __builtin_amdgcn_mfma_f32_16x16x32_f16(aQ[kk], bK, s[n], 0, 0, 0);
      }

    // online softmax (rows r: q-row = w*16 + (lane>>4)*4 + r)
    float p[4][4];
#pragma unroll
    for (int r = 0; r < 4; ++r) {
      float v0 = fmaxf(fmaxf(s[0][r], s[1][r]), fmaxf(s[2][r], s[3][r]));
#pragma unroll
      for (int off = 1; off < 16; off <<= 1) v0 = fmaxf(v0, __shfl_xor(v0, off, 64));
      float mnew = fmaxf(mr[r], v0);
      float sc = __expf(mr[r] - mnew);
      float su = 0.f;
#pragma unroll
      for (int n = 0; n < 4; ++n) { float e = __expf(s[n][r] - mnew); p[n][r] = e; su += e; }
#pragma unroll
      for (int off = 1; off < 16; off <<= 1) su += __shfl_xor(su, off, 64);
      lr[r] = lr[r] * sc + su;
      mr[r] = mnew;
#pragma unroll
      for (int n = 0; n < 4; ++n) accO[n][r] *= sc;
    }
    // P -> LDS (wave-private region; in-wave lgkm ordering suffices)
#pragma unroll
    for (int n = 0; n < 4; ++n)
#pragma unroll
      for (int r = 0; r < 4; ++r)
        Plds[w][(lane >> 4) * 4 + r][n * 16 + (lane & 15)] = (_Float16)p[n][r];

    // O += P V
#pragma unroll
    for (int kk = 0; kk < 2; ++kk) {
      half8 aP = *(const half8*)&Plds[w][lane & 15][kk * 32 + 8 * (lane >> 4)];
#pragma unroll
      for (int n = 0; n < 4; ++n) {
        half8 bV = *(const half8*)&Vt[n * 16 + (lane & 15)][kk * 32 + 8 * (lane >> 4)];
        accO[n] = __builtin_amdgcn_mfma_f32_16x16x32_f16(aP, bV, accO[n], 0, 0, 0);
      }
    }
  }

  // epilogue
#pragma unroll
  for (int n = 0; n < 4; ++n)
#pragma unroll
    for (int r = 0; r < 4; ++r) {
      int row = q0 + w * 16 + (lane >> 4) * 4 + r;
      Ovec[base + (size_t)row * D_MODEL + n * 16 + (lane & 15)] =
          (_Float16)(accO[n][r] / lr[r]);
    }
}

// ---------------- residual + LayerNorm -------------------------------------
__global__ __launch_bounds__(256)
void ln_res(const float* __restrict__ h, const _Float16* __restrict__ ao,
            const float* __restrict__ gamma, const float* __restrict__ beta,
            float* __restrict__ out) {
  int row = blockIdx.x;
  int t = threadIdx.x, lane = t & 63, w = t >> 6;
  const float* hp = h + (size_t)row * D_MODEL;
  const _Float16* ap = ao + (size_t)row * D_MODEL;
  float4 hv = *(const float4*)&hp[t * 4];
  half4 av = *(const half4*)&ap[t * 4];
  float x[4];
  x[0] = hv.x + (float)av[0]; x[1] = hv.y + (float)av[1];
  x[2] = hv.z + (float)av[2]; x[3] = hv.w + (float)av[3];
  float sum = x[0] + x[1] + x[2] + x[3];
  float ssq = x[0]*x[0] + x[1]*x[1] + x[2]*x[2] + x[3]*x[3];
#pragma unroll
  for (int off = 1; off < 64; off <<= 1) {
    sum += __shfl_xor(sum, off, 64);
    ssq += __shfl_xor(ssq, off, 64);
  }
  __shared__ float rs[4], rq[4];
  if (lane == 0) { rs[w] = sum; rq[w] = ssq; }
  __syncthreads();
  sum = rs[0] + rs[1] + rs[2] + rs[3];
  ssq = rq[0] + rq[1] + rq[2] + rq[3];
  float mu = sum * (1.f / 1024.f);
  float var = ssq * (1.f / 1024.f) - mu * mu;
  float inv = rsqrtf(var + 1e-5f);
  float4 gv = *(const float4*)&gamma[t * 4];
  float4 bv = *(const float4*)&beta[t * 4];
  float4 ov;
  ov.x = (x[0] - mu) * inv * gv.x + bv.x;
  ov.y = (x[1] - mu) * inv * gv.y + bv.y;
  ov.z = (x[2] - mu) * inv * gv.z + bv.z;
  ov.w = (x[3] - mu) * inv * gv.w + bv.w;
  *(float4*)&out[(size_t)row * D_MODEL + t * 4] = ov;
}

// ---------------------------------------------------------------------------
extern "C" void kernel_launch(void* const* d_in, const int* in_sizes, int n_in,
                              void* d_out, int out_size, void* d_ws, size_t ws_size,
                              hipStream_t stream) {
  const float* h     = (const float*)d_in[0];
  const float* Wq    = (const float*)d_in[1];
  const float* Wk    = (const float*)d_in[2];
  const float* Wv    = (const float*)d_in[3];
  const float* Wo    = (const float*)d_in[4];
  const float* gamma = (const float*)d_in[5];
  const float* beta  = (const float*)d_in[6];
  float* out = (float*)d_out;

  // workspace carve (fp16): WT 8MB | X 16MB | QKV 48MB   (total 72MB)
  char* ws = (char*)d_ws;
  _Float16* WT  = (_Float16*)ws;                                   // [4][1024][1024]
  _Float16* X   = (_Float16*)(ws + (size_t)8  * 1024 * 1024);      // also attn_vec
  _Float16* QKV = (_Float16*)(ws + (size_t)24 * 1024 * 1024);      // Q|K|V; later attn_out
  const size_t WSTRIDE = (size_t)D_MODEL * D_MODEL;                // 1M halves
  const size_t CSTRIDE = (size_t)NTOK * D_MODEL;                   // 8M halves

  wtrans<<<dim3(16, 16, 4), 256, 0, stream>>>(Wq, Wk, Wv, Wo, WT);
  cvt_h<<<dim3(NTOK * D_MODEL / 1024), 256, 0, stream>>>(h, X);
  // Q/K/V projections
  gemm_tn<<<dim3(8, 64, 3), 256, 0, stream>>>(X, WT, QKV, WSTRIDE, CSTRIDE);
  // flash attention -> attn_vec (reuses X)
  attn<<<dim3(SEQ / 64, 64), 256, 0, stream>>>(QKV, QKV + CSTRIDE, QKV + 2 * CSTRIDE, X);
  // output projection -> attn_out fp16 (reuses QKV front)
  gemm_tn<<<dim3(8, 64, 1), 256, 0, stream>>>(X, WT + 3 * WSTRIDE, QKV, 0, 0);
  // residual + LayerNorm
  ln_res<<<dim3(NTOK), 256, 0, stream>>>(h, QKV, gamma, beta, out);

  (void)in_sizes; (void)n_in; (void)out_size; (void)ws_size;
}

// Round 7
// 352.574 us; speedup vs baseline: 1.4322x; 1.4322x over previous
//
#include <hip/hip_runtime.h>
#include <hip/hip_bf16.h>

// ---------------------------------------------------------------------------
// MultiHeadAttn: B=4 S=2048 D=1024 H=16 DH=64, post-LN residual, no mask.
// fp16 MFMA pipeline: WT/X prep -> QKV GEMM -> flash attn -> Wo GEMM -> LN.
// R5: attn = swapped QK^T (in-lane softmax, in-reg P) + V^T via XOR-swizzled
//     LDS store (plain ds ops, both-sides swizzle; no tr_read, no Plds).
// ---------------------------------------------------------------------------

typedef __attribute__((ext_vector_type(8))) _Float16 half8;
typedef __attribute__((ext_vector_type(4))) _Float16 half4;
typedef __attribute__((ext_vector_type(4))) float f32x4;

#define D_MODEL 1024
#define SEQ     2048
#define NHEAD   16
#define HDIM    64
#define NTOK    8192          // B*S

// ---------------- async global->LDS, 16B, wave-uniform LDS base -------------
__device__ __forceinline__ void gload_lds16(const _Float16* g, _Float16* l) {
  __builtin_amdgcn_global_load_lds(
      (const __attribute__((address_space(1))) void*)g,
      (__attribute__((address_space(3))) void*)l, 16, 0, 0);
}

// Stage ROWS x 64-half tile (row-major, 128B/row) into LDS, XOR-swizzled
// source so that reads use granule (G ^ (row&7)). Dest is linear.
template<int ROWS>
__device__ __forceinline__ void stage_swz(const _Float16* __restrict__ g, int ldg,
                                          _Float16* lds, int t) {
  int lane = t & 63, w = t >> 6;
  int rr = lane >> 3, gcol = lane & 7;
#pragma unroll
  for (int i = 0; i < ROWS / 32; ++i) {
    int rowbase = i * 32 + w * 8;          // wave-uniform
    int row = rowbase + rr;                // per-lane
    int gsw = gcol ^ (row & 7);            // inverse swizzle on source
    gload_lds16(g + (size_t)row * ldg + gsw * 8, lds + rowbase * 64);
  }
}

// swizzled fragment read: 8 halves of row `row`, k-granule G = kk*4+(lane>>4)
__device__ __forceinline__ half8 lds_frag(const _Float16* base, int row, int kk, int lane) {
  int gg = (kk * 4 + (lane >> 4)) ^ (row & 7);
  return *(const half8*)(base + row * 64 + gg * 8);
}

// ---------------- weight transpose + fp32->fp16 (+fold SCALE into Wq) ------
__global__ __launch_bounds__(256)
void wtrans(const float* __restrict__ Wq, const float* __restrict__ Wk,
            const float* __restrict__ Wv, const float* __restrict__ Wo,
            _Float16* __restrict__ outAll) {
  __shared__ float tile[64][65];
  int z = blockIdx.z;
  const float* W = (z == 0) ? Wq : (z == 1) ? Wk : (z == 2) ? Wv : Wo;
  float scale = (z == 0) ? 0.125f : 1.0f;  // SCALE = 1/sqrt(64), exact pow2
  _Float16* out = outAll + (size_t)z * D_MODEL * D_MODEL;
  int n0 = blockIdx.x * 64, k0 = blockIdx.y * 64;
  int t = threadIdx.x, c = t & 63, rq = t >> 6;
#pragma unroll
  for (int i = 0; i < 16; ++i) {
    int r = rq * 16 + i;
    tile[r][c] = W[(size_t)(k0 + r) * D_MODEL + n0 + c];
  }
  __syncthreads();
#pragma unroll
  for (int i = 0; i < 16; ++i) {
    int r = rq * 16 + i;
    out[(size_t)(n0 + r) * D_MODEL + k0 + c] = (_Float16)(tile[c][r] * scale);
  }
}

// ---------------- h fp32 -> fp16 -------------------------------------------
__global__ __launch_bounds__(256)
void cvt_h(const float* __restrict__ in, _Float16* __restrict__ out) {
  int i = (blockIdx.x * 256 + threadIdx.x) * 4;
  float4 v = *(const float4*)&in[i];
  half4 o;
  o[0] = (_Float16)v.x; o[1] = (_Float16)v.y;
  o[2] = (_Float16)v.z; o[3] = (_Float16)v.w;
  *(half4*)&out[i] = o;
}

// ---------------- GEMM: C[M,N] = A[M,K] * Bt[N,K]^T, fp16 in, fp16 out -----
// 128x128 tile, BK=64, 4 waves (each 64x64), double-buffered LDS,
// global_load_lds x16B staging. grid=(N/128, M/128, batch).
__global__ __launch_bounds__(256, 2)
void gemm_tn(const _Float16* __restrict__ A, const _Float16* __restrict__ BtBase,
             _Float16* __restrict__ CBase, size_t strideB, size_t strideC) {
  constexpr int N = D_MODEL, K = D_MODEL;
  const _Float16* Bt = BtBase + strideB * blockIdx.z;
  _Float16* C = CBase + strideC * blockIdx.z;
  __shared__ __align__(16) _Float16 As[2][128 * 64];
  __shared__ __align__(16) _Float16 Bs[2][128 * 64];
  int t = threadIdx.x, lane = t & 63, w = t >> 6;
  int wr = w >> 1, wc = w & 1;
  const _Float16* Ab = A + (size_t)blockIdx.y * 128 * K;
  const _Float16* Bb = Bt + (size_t)blockIdx.x * 128 * K;

  f32x4 acc[4][4];
#pragma unroll
  for (int m = 0; m < 4; ++m)
#pragma unroll
    for (int n = 0; n < 4; ++n) acc[m][n] = f32x4{0.f, 0.f, 0.f, 0.f};

  stage_swz<128>(Ab, K, As[0], t);
  stage_swz<128>(Bb, K, Bs[0], t);
  __syncthreads();

  constexpr int NT = K / 64;
  for (int kt = 0; kt < NT; ++kt) {
    int cur = kt & 1;
    if (kt + 1 < NT) {
      stage_swz<128>(Ab + (kt + 1) * 64, K, As[cur ^ 1], t);
      stage_swz<128>(Bb + (kt + 1) * 64, K, Bs[cur ^ 1], t);
    }
#pragma unroll
    for (int kk = 0; kk < 2; ++kk) {
      half8 af[4], bf[4];
#pragma unroll
      for (int m = 0; m < 4; ++m)
        af[m] = lds_frag(As[cur], wr * 64 + m * 16 + (lane & 15), kk, lane);
#pragma unroll
      for (int n = 0; n < 4; ++n)
        bf[n] = lds_frag(Bs[cur], wc * 64 + n * 16 + (lane & 15), kk, lane);
#pragma unroll
      for (int m = 0; m < 4; ++m)
#pragma unroll
        for (int n = 0; n < 4; ++n)
          acc[m][n] = __builtin_amdgcn_mfma_f32_16x16x32_f16(af[m], bf[n], acc[m][n], 0, 0, 0);
    }
    __syncthreads();   // drains vmcnt (next bufs staged) + protects reuse
  }

  // epilogue: D row=(lane>>4)*4+r, col=lane&15 (m89-verified)
#pragma unroll
  for (int m = 0; m < 4; ++m)
#pragma unroll
    for (int n = 0; n < 4; ++n)
#pragma unroll
      for (int r = 0; r < 4; ++r) {
        int row = blockIdx.y * 128 + wr * 64 + m * 16 + (lane >> 4) * 4 + r;
        int col = blockIdx.x * 128 + wc * 64 + n * 16 + (lane & 15);
        C[(size_t)row * N + col] = (_Float16)acc[m][n][r];
      }
}

// ---------------- flash attention (swapped QK^T + swizzled V^T store) -------
// grid = (S/64, B*H), 256 threads = 4 waves, wave w owns q rows [w*16,w*16+16).
// S^T = mfma(K, Q): lane (g=lane>>4, c=lane&15) holds S[key=n*16+4g+r][q=w*16+c]
// -> softmax per-lane over 16 keys + 2 shfl_xor rounds; P stays in registers.
// V^T in LDS with granule-XOR swizzle: phys(d,key)=d*64+((key>>2)^(d&15))*4+(key&3).
//   writes: lane l owns key=l -> granules (l>>2)^const, 2-way (free).
//   reads:  b64 at granule (8kk+4hi+g)^c -> uniform 4 dwords/bank (floor).
__global__ __launch_bounds__(256, 2)
void attn(const _Float16* __restrict__ Q, const _Float16* __restrict__ Kg,
          const _Float16* __restrict__ V, _Float16* __restrict__ Ovec) {
  __shared__ __align__(16) _Float16 Ks[64 * 64];
  __shared__ __align__(16) _Float16 Vt[64 * 64];
  int t = threadIdx.x, lane = t & 63, w = t >> 6;
  int g = lane >> 4, c = lane & 15;
  int q0 = blockIdx.x * 64;
  int bh = blockIdx.y, b = bh >> 4, h = bh & 15;
  size_t base = ((size_t)b * SEQ) * D_MODEL + h * HDIM;

  // Q fragment (B-operand of swapped QK^T): lane supplies Q[q0+w*16+c][32kk+8g+j]
  half8 aQ[2];
  {
    int row = q0 + w * 16 + c;
    const _Float16* qp = Q + base + (size_t)row * D_MODEL;
#pragma unroll
    for (int kk = 0; kk < 2; ++kk) aQ[kk] = *(const half8*)&qp[kk * 32 + 8 * g];
  }

  float mr = -1e30f, lr = 0.f;
  f32x4 accO[4];   // accO[n][r] = O[q0+w*16+4g+r][n*16+c]
#pragma unroll
  for (int n = 0; n < 4; ++n) accO[n] = f32x4{0.f, 0.f, 0.f, 0.f};

  for (int kv0 = 0; kv0 < SEQ; kv0 += 64) {
    __syncthreads();  // previous tile's Ks/Vt reads complete
    // stage K tile (row-major, read-swizzled, async)
    stage_swz<64>(Kg + base + (size_t)kv0 * D_MODEL, D_MODEL, Ks, t);
    // stage V^T: lane owns key = lane; wave w covers d = [8w..8w+8) and +32
    {
      const _Float16* vp = V + base + (size_t)(kv0 + lane) * D_MODEL + 8 * w;
      half8 vv0 = *(const half8*)vp;
      half8 vv1 = *(const half8*)(vp + 32);
      int tw = (lane >> 2) ^ ((w & 1) * 8);
      int l3 = lane & 3;
      int d0 = 8 * w;
#pragma unroll
      for (int j = 0; j < 8; ++j) {
        int col = ((tw ^ j) << 2) + l3;
        Vt[(d0 + j) * 64 + col] = vv0[j];
        Vt[(d0 + 32 + j) * 64 + col] = vv1[j];   // (d+32)&15 == (d)&15
      }
    }
    __syncthreads();  // vmcnt drained (Ks) + Vt visible

    // S^T: s[n][r] = S[key=kv0+n*16+4g+r][q=q0+w*16+c]
    f32x4 s[4];
#pragma unroll
    for (int n = 0; n < 4; ++n) s[n] = f32x4{0.f, 0.f, 0.f, 0.f};
#pragma unroll
    for (int kk = 0; kk < 2; ++kk)
#pragma unroll
      for (int n = 0; n < 4; ++n) {
        half8 aK = lds_frag(Ks, n * 16 + c, kk, lane);   // A = K
        s[n] = __builtin_amdgcn_mfma_f32_16x16x32_f16(aK, aQ[kk], s[n], 0, 0, 0);
      }

    // in-lane softmax for q = q0+w*16+c over this tile's 16 held keys,
    // then reduce across the 4 lane-groups (keys interleave by g).
    float vmax = s[0][0];
#pragma unroll
    for (int n = 0; n < 4; ++n)
#pragma unroll
      for (int r = 0; r < 4; ++r) vmax = fmaxf(vmax, s[n][r]);
    vmax = fmaxf(vmax, __shfl_xor(vmax, 16, 64));
    vmax = fmaxf(vmax, __shfl_xor(vmax, 32, 64));
    float mnew = fmaxf(mr, vmax);
    float sc = __expf(mr - mnew);
    float p[4][4];
    float lsum = 0.f;
#pragma unroll
    for (int n = 0; n < 4; ++n)
#pragma unroll
      for (int r = 0; r < 4; ++r) {
        float e = __expf(s[n][r] - mnew);
        p[n][r] = e; lsum += e;
      }
    lsum += __shfl_xor(lsum, 16, 64);
    lsum += __shfl_xor(lsum, 32, 64);
    lr = lr * sc + lsum;
    mr = mnew;
    // rescale accO rows (q' = 4g+r): fetch sc computed by lane c==q' (group 0)
    float scq[4];
#pragma unroll
    for (int r = 0; r < 4; ++r) scq[r] = __shfl(sc, 4 * g + r, 64);
#pragma unroll
    for (int n = 0; n < 4; ++n)
#pragma unroll
      for (int r = 0; r < 4; ++r) accO[n][r] *= scq[r];

    // pack P fragments in-register: aP[kk][j] = P[q][key=32kk+16(j>>2)+4g+(j&3)]
    half8 aP[2];
#pragma unroll
    for (int kk = 0; kk < 2; ++kk)
#pragma unroll
      for (int j = 0; j < 8; ++j)
        aP[kk][j] = (_Float16)p[2 * kk + (j >> 2)][j & 3];

    // O += P V : bV[4hi+j] = V[32kk+16hi+4g+j][16n+c] via swizzled b64 reads
#pragma unroll
    for (int kk = 0; kk < 2; ++kk)
#pragma unroll
      for (int n = 0; n < 4; ++n) {
        const _Float16* rowp = Vt + (size_t)(16 * n + c) * 64;
        half4 lo = *(const half4*)&rowp[((8 * kk + g) ^ c) << 2];
        half4 hi = *(const half4*)&rowp[((8 * kk + 4 + g) ^ c) << 2];
        half8 bV;
#pragma unroll
        for (int j = 0; j < 4; ++j) { bV[j] = lo[j]; bV[4 + j] = hi[j]; }
        accO[n] = __builtin_amdgcn_mfma_f32_16x16x32_f16(aP[kk], bV, accO[n], 0, 0, 0);
      }
  }

  // epilogue: row q = q0+w*16+4g+r needs lr from lane c==q' (group 0)
  float lrq[4];
#pragma unroll
  for (int r = 0; r < 4; ++r) lrq[r] = __shfl(lr, 4 * g + r, 64);
#pragma unroll
  for (int n = 0; n < 4; ++n)
#pragma unroll
    for (int r = 0; r < 4; ++r) {
      int row = q0 + w * 16 + 4 * g + r;
      Ovec[base + (size_t)row * D_MODEL + n * 16 + c] =
          (_Float16)(accO[n][r] / lrq[r]);
    }
}

// ---------------- residual + LayerNorm -------------------------------------
__global__ __launch_bounds__(256)
void ln_res(const float* __restrict__ h, const _Float16* __restrict__ ao,
            const float* __restrict__ gamma, const float* __restrict__ beta,
            float* __restrict__ out) {
  int row = blockIdx.x;
  int t = threadIdx.x, lane = t & 63, w = t >> 6;
  const float* hp = h + (size_t)row * D_MODEL;
  const _Float16* ap = ao + (size_t)row * D_MODEL;
  float4 hv = *(const float4*)&hp[t * 4];
  half4 av = *(const half4*)&ap[t * 4];
  float x[4];
  x[0] = hv.x + (float)av[0]; x[1] = hv.y + (float)av[1];
  x[2] = hv.z + (float)av[2]; x[3] = hv.w + (float)av[3];
  float sum = x[0] + x[1] + x[2] + x[3];
  float ssq = x[0]*x[0] + x[1]*x[1] + x[2]*x[2] + x[3]*x[3];
#pragma unroll
  for (int off = 1; off < 64; off <<= 1) {
    sum += __shfl_xor(sum, off, 64);
    ssq += __shfl_xor(ssq, off, 64);
  }
  __shared__ float rs[4], rq[4];
  if (lane == 0) { rs[w] = sum; rq[w] = ssq; }
  __syncthreads();
  sum = rs[0] + rs[1] + rs[2] + rs[3];
  ssq = rq[0] + rq[1] + rq[2] + rq[3];
  float mu = sum * (1.f / 1024.f);
  float var = ssq * (1.f / 1024.f) - mu * mu;
  float inv = rsqrtf(var + 1e-5f);
  float4 gv = *(const float4*)&gamma[t * 4];
  float4 bv = *(const float4*)&beta[t * 4];
  float4 ov;
  ov.x = (x[0] - mu) * inv * gv.x + bv.x;
  ov.y = (x[1] - mu) * inv * gv.y + bv.y;
  ov.z = (x[2] - mu) * inv * gv.z + bv.z;
  ov.w = (x[3] - mu) * inv * gv.w + bv.w;
  *(float4*)&out[(size_t)row * D_MODEL + t * 4] = ov;
}

// ---------------------------------------------------------------------------
extern "C" void kernel_launch(void* const* d_in, const int* in_sizes, int n_in,
                              void* d_out, int out_size, void* d_ws, size_t ws_size,
                              hipStream_t stream) {
  const float* h     = (const float*)d_in[0];
  const float* Wq    = (const float*)d_in[1];
  const float* Wk    = (const float*)d_in[2];
  const float* Wv    = (const float*)d_in[3];
  const float* Wo    = (const float*)d_in[4];
  const float* gamma = (const float*)d_in[5];
  const float* beta  = (const float*)d_in[6];
  float* out = (float*)d_out;

  // workspace carve (fp16): WT 8MB | X 16MB | QKV 48MB   (total 72MB)
  char* ws = (char*)d_ws;
  _Float16* WT  = (_Float16*)ws;                                   // [4][1024][1024]
  _Float16* X   = (_Float16*)(ws + (size_t)8  * 1024 * 1024);      // also attn_vec
  _Float16* QKV = (_Float16*)(ws + (size_t)24 * 1024 * 1024);      // Q|K|V; later attn_out
  const size_t WSTRIDE = (size_t)D_MODEL * D_MODEL;                // 1M halves
  const size_t CSTRIDE = (size_t)NTOK * D_MODEL;                   // 8M halves

  wtrans<<<dim3(16, 16, 4), 256, 0, stream>>>(Wq, Wk, Wv, Wo, WT);
  cvt_h<<<dim3(NTOK * D_MODEL / 1024), 256, 0, stream>>>(h, X);
  // Q/K/V projections
  gemm_tn<<<dim3(8, 64, 3), 256, 0, stream>>>(X, WT, QKV, WSTRIDE, CSTRIDE);
  // flash attention -> attn_vec (reuses X)
  attn<<<dim3(SEQ / 64, 64), 256, 0, stream>>>(QKV, QKV + CSTRIDE, QKV + 2 * CSTRIDE, X);
  // output projection -> attn_out fp16 (reuses QKV front)
  gemm_tn<<<dim3(8, 64, 1), 256, 0, stream>>>(X, WT + 3 * WSTRIDE, QKV, 0, 0);
  // residual + LayerNorm
  ln_res<<<dim3(NTOK), 256, 0, stream>>>(h, QKV, gamma, beta, out);

  (void)in_sizes; (void)n_in; (void)out_size; (void)ws_size;
}